// Round 6
// baseline (383.663 us; speedup 1.0000x reference)
//
#include <hip/hip_runtime.h>
#include <stdint.h>

typedef float vfloat4 __attribute__((ext_vector_type(4)));

constexpr int CHUNK = 4096;
constexpr int TG    = 16;
constexpr int VT    = 2048;   // k1a v-tile width (floats)
constexpr int MAXNG = 24;     // max h-groups

// ---------------------------------------------------------------------------
// Kernel 1a: partial GEMV, lane-stride-4 coalesced. Thread owns columns
// v = vt*VT + tid + 256*j (j=0..7): every dword load is a contiguous 256B
// wave transaction (4 lines/inst) -- no transaction amplification.
// ---------------------------------------------------------------------------
__global__ __launch_bounds__(256) void fuse_partial_kernel(
    const float* __restrict__ Wemb,   // [H][V] row-major
    const float* __restrict__ Wcls,   // [2][H]
    float* __restrict__ part,         // [NG][2][Vp]
    const int V, const int Vp, const int H, const int NG, const int NVT)
{
    __shared__ float sW0[1024];
    __shared__ float sW1[1024];
    for (int i = threadIdx.x; i < H; i += 256) { sW0[i] = Wcls[i]; sW1[i] = Wcls[H + i]; }
    __syncthreads();

    const int vt = blockIdx.x % NVT;
    const int g  = blockIdx.x / NVT;
    const int HS = (H + NG - 1) / NG;
    const int h0 = g * HS;
    const int h1 = min(H, h0 + HS);
    const int base = vt * VT + (int)threadIdx.x;

    float a0[8], a1[8];
    #pragma unroll
    for (int j = 0; j < 8; ++j) { a0[j] = 0.f; a1[j] = 0.f; }

    if ((vt + 1) * VT <= V) {
        for (int h = h0; h < h1; ++h) {
            const float* p = Wemb + (size_t)h * (size_t)V + base;
            const float w0 = sW0[h], w1 = sW1[h];
            #pragma unroll
            for (int j = 0; j < 8; ++j) {
                float x = p[j * 256];
                a0[j] = fmaf(w0, x, a0[j]);
                a1[j] = fmaf(w1, x, a1[j]);
            }
        }
        float* o0 = part + (size_t)g * 2 * (size_t)Vp + base;
        #pragma unroll
        for (int j = 0; j < 8; ++j) { o0[j * 256] = a0[j]; o0[Vp + j * 256] = a1[j]; }
    } else {
        // tail v-tile: guarded
        for (int h = h0; h < h1; ++h) {
            const float* p = Wemb + (size_t)h * (size_t)V;
            const float w0 = sW0[h], w1 = sW1[h];
            #pragma unroll
            for (int j = 0; j < 8; ++j) {
                const int v = base + j * 256;
                if (v < V) {
                    float x = p[v];
                    a0[j] = fmaf(w0, x, a0[j]);
                    a1[j] = fmaf(w1, x, a1[j]);
                }
            }
        }
        float* o0 = part + (size_t)g * 2 * (size_t)Vp;
        #pragma unroll
        for (int j = 0; j < 8; ++j) {
            const int v = base + j * 256;
            if (v < V) { o0[v] = a0[j]; o0[Vp + v] = a1[j]; }
        }
    }
}

// ---------------------------------------------------------------------------
// Kernel 1b: reduce NG partial segments, apply token_mask, emit wf2 (float2).
// ---------------------------------------------------------------------------
__global__ __launch_bounds__(256) void fuse_reduce_kernel(
    const float* __restrict__ part,   // [NG][2][Vp]
    const float* __restrict__ tmask,  // [V]
    float2* __restrict__ wf2,         // [V]
    const int V, const int Vp, const int NG)
{
    const int v = blockIdx.x * 256 + threadIdx.x;
    if (v >= V) return;
    float s0 = 0.f, s1 = 0.f;
    for (int g = 0; g < NG; ++g) {
        const float* p0 = part + (size_t)g * 2 * (size_t)Vp;
        s0 += p0[v];
        s1 += p0[Vp + v];
    }
    const float m = tmask[v];
    wf2[v] = make_float2(s0 * m, s1 * m);
}

// ---------------------------------------------------------------------------
// Kernel 1 (fallback, column version) — only if ws can't hold k1a partials.
// ---------------------------------------------------------------------------
__global__ __launch_bounds__(256) void fuse_weights_kernel(
    const float* __restrict__ Wemb, const float* __restrict__ tmask,
    const float* __restrict__ Wcls, float2* __restrict__ wf2, int V, int H)
{
    __shared__ float sW0[1024];
    __shared__ float sW1[1024];
    __shared__ float part[4][64][2];

    for (int i = threadIdx.x; i < H; i += blockDim.x) {
        sW0[i] = Wcls[i];
        sW1[i] = Wcls[H + i];
    }
    __syncthreads();

    const int vl = threadIdx.x & 63;
    const int hg = threadIdx.x >> 6;
    const int v  = blockIdx.x * 64 + vl;

    float a0 = 0.f, a1 = 0.f;
    if (v < V) {
        for (int h = hg; h < H; h += 4) {
            float w = Wemb[(size_t)h * (size_t)V + v];
            a0 = fmaf(w, sW0[h], a0);
            a1 = fmaf(w, sW1[h], a1);
        }
    }
    part[hg][vl][0] = a0;
    part[hg][vl][1] = a1;
    __syncthreads();

    if (hg == 0 && v < V) {
        float r0 = (part[0][vl][0] + part[1][vl][0]) + (part[2][vl][0] + part[3][vl][0]);
        float r1 = (part[0][vl][1] + part[1][vl][1]) + (part[2][vl][1] + part[3][vl][1]);
        float m = tmask[v];
        wf2[v] = make_float2(r0 * m, r1 * m);
    }
}

// ---------------------------------------------------------------------------
// Kernel 2: class-grouped tokens + shifted windows + register weights.
// V ≡ 1 (mod 4)  =>  row misalignment class = t mod 4. A block handles 16
// tokens of ONE class (t = r + 64q + 4k) and the v-window [h + c*CHUNK, ...)
// with h=(4-r)&3, so (t*V + window start) ≡ 0 mod 4: EVERY emb load is an
// aligned global_load_dwordx4 (16 lines/KB -- no transaction amplification).
// Weights live in 32 registers per thread (de-interleaved once per block);
// no LDS at all in the hot loop. Head floats v<h are folded into c==0 blocks.
// ---------------------------------------------------------------------------
__global__ __launch_bounds__(256) void partial_kernel(
    const float* __restrict__ emb,   // [T][V]
    const float2* __restrict__ wf2,  // [V] interleaved {w0, w1}
    float4* __restrict__ part,       // [NC][T]  {S, D0, D1, pad}
    const int V, const int T, const int NC)
{
    __shared__ float red[4][TG][3];

    const int tid = threadIdx.x;
    const int c   = blockIdx.x % NC;
    const int g   = blockIdx.x / NC;
    const int r   = g & 3;                 // token class: t ≡ r (mod 4)
    const int q   = g >> 2;
    const int h   = (4 - r) & 3;           // window shift for 16B alignment
    const int wstart = h + c * CHUNK;
    const int wlen   = min(CHUNK, V - wstart);
    const int voff   = tid << 2;
    const int wv     = tid >> 6;           // wave id

    if (wlen == CHUNK) {
        // de-interleave this thread's weights into registers (from L2, once)
        vfloat4 w0v[4], w1v[4];
        #pragma unroll
        for (int jj = 0; jj < 4; ++jj) {
            float2 f[4];
            __builtin_memcpy(f, wf2 + (wstart + voff + jj * 1024), 32);
            w0v[jj] = (vfloat4){f[0].x, f[1].x, f[2].x, f[3].x};
            w1v[jj] = (vfloat4){f[0].y, f[1].y, f[2].y, f[3].y};
        }

        for (int tk = 0; tk < TG; ++tk) {
            const int t = r + 64 * q + 4 * tk;
            const float* rp = emb + (size_t)t * (size_t)V + wstart;  // 16B-aligned
            float s = 0.f, d0 = 0.f, d1 = 0.f;
            #pragma unroll
            for (int jj = 0; jj < 4; ++jj) {
                const vfloat4 ev = *(const vfloat4*)(rp + voff + jj * 1024);
                s += (ev.x + ev.y) + (ev.z + ev.w);
                d0 = fmaf(ev.x, w0v[jj].x, d0);
                d0 = fmaf(ev.y, w0v[jj].y, d0);
                d0 = fmaf(ev.z, w0v[jj].z, d0);
                d0 = fmaf(ev.w, w0v[jj].w, d0);
                d1 = fmaf(ev.x, w1v[jj].x, d1);
                d1 = fmaf(ev.y, w1v[jj].y, d1);
                d1 = fmaf(ev.z, w1v[jj].z, d1);
                d1 = fmaf(ev.w, w1v[jj].w, d1);
            }
            if (c == 0 && tid < h) {       // head floats v in [0, h)
                const float e = emb[(size_t)t * (size_t)V + tid];
                const float2 w = wf2[tid];
                s += e; d0 = fmaf(e, w.x, d0); d1 = fmaf(e, w.y, d1);
            }
            #pragma unroll
            for (int off = 32; off > 0; off >>= 1) {
                s  += __shfl_xor(s,  off);
                d0 += __shfl_xor(d0, off);
                d1 += __shfl_xor(d1, off);
            }
            if ((tid & 63) == 0) {
                red[wv][tk][0] = s; red[wv][tk][1] = d0; red[wv][tk][2] = d1;
            }
        }
    } else {
        // tail chunk (wlen = 1113-h): weights straight from L2-resident wf2
        const int nb4 = wlen >> 2;
        const int rem = wlen & 3;
        for (int tk = 0; tk < TG; ++tk) {
            const int t = r + 64 * q + 4 * tk;
            const float* rp = emb + (size_t)t * (size_t)V + wstart;  // 16B-aligned
            float s = 0.f, d0 = 0.f, d1 = 0.f;
            for (int j = tid; j < nb4; j += 256) {
                const int v4 = j << 2;
                const vfloat4 ev = *(const vfloat4*)(rp + v4);
                float2 f[4];
                __builtin_memcpy(f, wf2 + (wstart + v4), 32);
                s += (ev.x + ev.y) + (ev.z + ev.w);
                d0 = fmaf(ev.x, f[0].x, d0);
                d0 = fmaf(ev.y, f[1].x, d0);
                d0 = fmaf(ev.z, f[2].x, d0);
                d0 = fmaf(ev.w, f[3].x, d0);
                d1 = fmaf(ev.x, f[0].y, d1);
                d1 = fmaf(ev.y, f[1].y, d1);
                d1 = fmaf(ev.z, f[2].y, d1);
                d1 = fmaf(ev.w, f[3].y, d1);
            }
            if (tid < rem) {
                const int v = (nb4 << 2) + tid;
                const float e = rp[v];
                const float2 w = wf2[wstart + v];
                s += e; d0 = fmaf(e, w.x, d0); d1 = fmaf(e, w.y, d1);
            }
            #pragma unroll
            for (int off = 32; off > 0; off >>= 1) {
                s  += __shfl_xor(s,  off);
                d0 += __shfl_xor(d0, off);
                d1 += __shfl_xor(d1, off);
            }
            if ((tid & 63) == 0) {
                red[wv][tk][0] = s; red[wv][tk][1] = d0; red[wv][tk][2] = d1;
            }
        }
    }
    __syncthreads();

    if (tid < TG) {
        const float S  = (red[0][tid][0] + red[1][tid][0]) + (red[2][tid][0] + red[3][tid][0]);
        const float D0 = (red[0][tid][1] + red[1][tid][1]) + (red[2][tid][1] + red[3][tid][1]);
        const float D1 = (red[0][tid][2] + red[1][tid][2]) + (red[2][tid][2] + red[3][tid][2]);
        const int t = r + 64 * q + 4 * tid;
        part[(size_t)c * T + t] = make_float4(S, D0, D1, 0.f);
    }
}

// ---------------------------------------------------------------------------
// Kernel 3: finalize. out[t] = D/S + b. Fixed summation order.
// ---------------------------------------------------------------------------
__global__ __launch_bounds__(256) void finalize_kernel(
    const float4* __restrict__ part, const float* __restrict__ bcls,
    float2* __restrict__ out, const int T, const int NC)
{
    const int t = blockIdx.x * 256 + threadIdx.x;
    if (t >= T) return;
    float S = 0.f, D0 = 0.f, D1 = 0.f;
    for (int c = 0; c < NC; ++c) {
        float4 p = part[(size_t)c * T + t];
        S += p.x; D0 += p.y; D1 += p.z;
    }
    out[t] = make_float2(D0 / S + bcls[0], D1 / S + bcls[1]);
}

extern "C" void kernel_launch(void* const* d_in, const int* in_sizes, int n_in,
                              void* d_out, int out_size, void* d_ws, size_t ws_size,
                              hipStream_t stream) {
    const float* emb   = (const float*)d_in[0];   // [B,S,V] f32
    // d_in[1]: attention_masks (all-ones, unused by the math)
    const float* Wemb  = (const float*)d_in[2];   // [H,V] f32
    const float* tmask = (const float*)d_in[3];   // [V] f32
    const float* Wcls  = (const float*)d_in[4];   // [2,H] f32
    const float* bcls  = (const float*)d_in[5];   // [2] f32

    const int V  = in_sizes[3];                   // 50265 (V mod 4 == 1)
    const int T  = in_sizes[1];                   // B*S = 8192 (mult of 64)
    const int H  = in_sizes[2] / V;               // 768
    const int NC = (V + CHUNK - 1) / CHUNK;       // 13
    const int Vp = (V + 7) & ~7;

    // ws layout: [wf2: V float2][k2 partials: NC*T float4][k1 partials]
    float2* wf2 = (float2*)d_ws;
    const size_t wf2_b   = (((size_t)V * 8) + 255) & ~(size_t)255;
    const size_t k2p_b   = (((size_t)NC * T * 16) + 255) & ~(size_t)255;
    float4* k2part = (float4*)((char*)d_ws + wf2_b);
    const size_t off_k1p = wf2_b + k2p_b;
    float*  k1part = (float*)((char*)d_ws + off_k1p);

    const size_t per_g = (size_t)2 * Vp * 4;
    int NG = 0;
    if (ws_size > off_k1p) NG = (int)((ws_size - off_k1p) / per_g);
    if (NG > MAXNG) NG = MAXNG;

    if (NG >= 2) {
        const int NVT = (V + VT - 1) / VT;        // 25
        fuse_partial_kernel<<<NVT * NG, 256, 0, stream>>>(Wemb, Wcls, k1part, V, Vp, H, NG, NVT);
        fuse_reduce_kernel<<<(V + 255) / 256, 256, 0, stream>>>(k1part, tmask, wf2, V, Vp, NG);
    } else {
        fuse_weights_kernel<<<(V + 63) / 64, 256, 0, stream>>>(Wemb, tmask, Wcls, wf2, V, H);
    }

    // Kernel 2: class-grouped (chunk x 16-token) partial sums
    const int blocks2 = NC * (T / TG);
    partial_kernel<<<blocks2, 256, 0, stream>>>(emb, wf2, k2part, V, T, NC);

    // Kernel 3: finalize logits
    finalize_kernel<<<(T + 255) / 256, 256, 0, stream>>>(k2part, bcls, (float2*)d_out, T, NC);
}

// Round 7
// 351.610 us; speedup vs baseline: 1.0912x; 1.0912x over previous
//
#include <hip/hip_runtime.h>
#include <stdint.h>

typedef float vfloat4 __attribute__((ext_vector_type(4)));

constexpr int CHUNK = 4096;
constexpr int TG    = 32;     // tokens per k2 block (halves wf2 re-reads vs 16)
constexpr int VT    = 2048;   // k1a v-tile width (floats)
constexpr int MAXNG = 41;     // 25*41 = 1025 blocks ~= 4.0 rounds of 256 CUs

// ---------------------------------------------------------------------------
// Kernel 1a: partial GEMV, lane-stride-4 coalesced (UNCHANGED loads -- control
// for the nt experiment in k2). Only NG/grid shape changed for tail balance.
// ---------------------------------------------------------------------------
__global__ __launch_bounds__(256) void fuse_partial_kernel(
    const float* __restrict__ Wemb,   // [H][V] row-major
    const float* __restrict__ Wcls,   // [2][H]
    float* __restrict__ part,         // [NG][2][Vp]
    const int V, const int Vp, const int H, const int NG, const int NVT)
{
    __shared__ float sW0[1024];
    __shared__ float sW1[1024];
    for (int i = threadIdx.x; i < H; i += 256) { sW0[i] = Wcls[i]; sW1[i] = Wcls[H + i]; }
    __syncthreads();

    const int vt = blockIdx.x % NVT;
    const int g  = blockIdx.x / NVT;
    const int HS = (H + NG - 1) / NG;
    const int h0 = g * HS;
    const int h1 = min(H, h0 + HS);
    const int base = vt * VT + (int)threadIdx.x;

    float a0[8], a1[8];
    #pragma unroll
    for (int j = 0; j < 8; ++j) { a0[j] = 0.f; a1[j] = 0.f; }

    if ((vt + 1) * VT <= V) {
        for (int h = h0; h < h1; ++h) {
            const float* p = Wemb + (size_t)h * (size_t)V + base;
            const float w0 = sW0[h], w1 = sW1[h];
            #pragma unroll
            for (int j = 0; j < 8; ++j) {
                float x = p[j * 256];
                a0[j] = fmaf(w0, x, a0[j]);
                a1[j] = fmaf(w1, x, a1[j]);
            }
        }
        float* o0 = part + (size_t)g * 2 * (size_t)Vp + base;
        #pragma unroll
        for (int j = 0; j < 8; ++j) { o0[j * 256] = a0[j]; o0[Vp + j * 256] = a1[j]; }
    } else {
        for (int h = h0; h < h1; ++h) {
            const float* p = Wemb + (size_t)h * (size_t)V;
            const float w0 = sW0[h], w1 = sW1[h];
            #pragma unroll
            for (int j = 0; j < 8; ++j) {
                const int v = base + j * 256;
                if (v < V) {
                    float x = p[v];
                    a0[j] = fmaf(w0, x, a0[j]);
                    a1[j] = fmaf(w1, x, a1[j]);
                }
            }
        }
        float* o0 = part + (size_t)g * 2 * (size_t)Vp;
        #pragma unroll
        for (int j = 0; j < 8; ++j) {
            const int v = base + j * 256;
            if (v < V) { o0[v] = a0[j]; o0[Vp + v] = a1[j]; }
        }
    }
}

// ---------------------------------------------------------------------------
// Kernel 1b: reduce NG partial segments, apply token_mask, emit wf2 (float2).
// ---------------------------------------------------------------------------
__global__ __launch_bounds__(256) void fuse_reduce_kernel(
    const float* __restrict__ part,   // [NG][2][Vp]
    const float* __restrict__ tmask,  // [V]
    float2* __restrict__ wf2,         // [V]
    const int V, const int Vp, const int NG)
{
    const int v = blockIdx.x * 256 + threadIdx.x;
    if (v >= V) return;
    float s0 = 0.f, s1 = 0.f;
    for (int g = 0; g < NG; ++g) {
        const float* p0 = part + (size_t)g * 2 * (size_t)Vp;
        s0 += p0[v];
        s1 += p0[Vp + v];
    }
    const float m = tmask[v];
    wf2[v] = make_float2(s0 * m, s1 * m);
}

// ---------------------------------------------------------------------------
// Kernel 1 (fallback, column version) — only if ws can't hold k1a partials.
// ---------------------------------------------------------------------------
__global__ __launch_bounds__(256) void fuse_weights_kernel(
    const float* __restrict__ Wemb, const float* __restrict__ tmask,
    const float* __restrict__ Wcls, float2* __restrict__ wf2, int V, int H)
{
    __shared__ float sW0[1024];
    __shared__ float sW1[1024];
    __shared__ float part[4][64][2];

    for (int i = threadIdx.x; i < H; i += blockDim.x) {
        sW0[i] = Wcls[i];
        sW1[i] = Wcls[H + i];
    }
    __syncthreads();

    const int vl = threadIdx.x & 63;
    const int hg = threadIdx.x >> 6;
    const int v  = blockIdx.x * 64 + vl;

    float a0 = 0.f, a1 = 0.f;
    if (v < V) {
        for (int h = hg; h < H; h += 4) {
            float w = Wemb[(size_t)h * (size_t)V + v];
            a0 = fmaf(w, sW0[h], a0);
            a1 = fmaf(w, sW1[h], a1);
        }
    }
    part[hg][vl][0] = a0;
    part[hg][vl][1] = a1;
    __syncthreads();

    if (hg == 0 && v < V) {
        float r0 = (part[0][vl][0] + part[1][vl][0]) + (part[2][vl][0] + part[3][vl][0]);
        float r1 = (part[0][vl][1] + part[1][vl][1]) + (part[2][vl][1] + part[3][vl][1]);
        float m = tmask[v];
        wf2[v] = make_float2(r0 * m, r1 * m);
    }
}

// ---------------------------------------------------------------------------
// Kernel 2: class-grouped tokens + shifted windows + register weights.
// NEW vs round 6: (a) ALL emb loads are nontemporal (read-once stream must
// not evict the L2-resident wf2), (b) TG=32 halves per-byte wf2 re-reads.
// t = r + 128q + 4k covers each residue class within a 128-token band.
// ---------------------------------------------------------------------------
__global__ __launch_bounds__(256) void partial_kernel(
    const float* __restrict__ emb,   // [T][V]
    const float2* __restrict__ wf2,  // [V] interleaved {w0, w1}
    float4* __restrict__ part,       // [NC][T]  {S, D0, D1, pad}
    const int V, const int T, const int NC)
{
    __shared__ float red[4][TG][3];

    const int tid = threadIdx.x;
    const int c   = blockIdx.x % NC;
    const int g   = blockIdx.x / NC;
    const int r   = g & 3;                 // token class: t ≡ r (mod 4)
    const int q   = g >> 2;                // 128-token band
    const int h   = (4 - r) & 3;           // window shift for 16B alignment
    const int wstart = h + c * CHUNK;
    const int wlen   = min(CHUNK, V - wstart);
    const int voff   = tid << 2;
    const int wv     = tid >> 6;           // wave id

    if (wlen == CHUNK) {
        // de-interleave this thread's weights into registers (cached reads)
        vfloat4 w0v[4], w1v[4];
        #pragma unroll
        for (int jj = 0; jj < 4; ++jj) {
            float2 f[4];
            __builtin_memcpy(f, wf2 + (wstart + voff + jj * 1024), 32);
            w0v[jj] = (vfloat4){f[0].x, f[1].x, f[2].x, f[3].x};
            w1v[jj] = (vfloat4){f[0].y, f[1].y, f[2].y, f[3].y};
        }

        for (int tk = 0; tk < TG; ++tk) {
            const int t = r + 128 * q + 4 * tk;
            const float* rp = emb + (size_t)t * (size_t)V + wstart;  // 16B-aligned
            float s = 0.f, d0 = 0.f, d1 = 0.f;
            #pragma unroll
            for (int jj = 0; jj < 4; ++jj) {
                const vfloat4 ev = __builtin_nontemporal_load(
                    (const vfloat4*)(rp + voff + jj * 1024));
                s += (ev.x + ev.y) + (ev.z + ev.w);
                d0 = fmaf(ev.x, w0v[jj].x, d0);
                d0 = fmaf(ev.y, w0v[jj].y, d0);
                d0 = fmaf(ev.z, w0v[jj].z, d0);
                d0 = fmaf(ev.w, w0v[jj].w, d0);
                d1 = fmaf(ev.x, w1v[jj].x, d1);
                d1 = fmaf(ev.y, w1v[jj].y, d1);
                d1 = fmaf(ev.z, w1v[jj].z, d1);
                d1 = fmaf(ev.w, w1v[jj].w, d1);
            }
            if (c == 0 && tid < h) {       // head floats v in [0, h)
                const float e = __builtin_nontemporal_load(
                    emb + (size_t)t * (size_t)V + tid);
                const float2 w = wf2[tid];
                s += e; d0 = fmaf(e, w.x, d0); d1 = fmaf(e, w.y, d1);
            }
            #pragma unroll
            for (int off = 32; off > 0; off >>= 1) {
                s  += __shfl_xor(s,  off);
                d0 += __shfl_xor(d0, off);
                d1 += __shfl_xor(d1, off);
            }
            if ((tid & 63) == 0) {
                red[wv][tk][0] = s; red[wv][tk][1] = d0; red[wv][tk][2] = d1;
            }
        }
    } else {
        // tail chunk: weights straight from L2-resident wf2
        const int nb4 = wlen >> 2;
        const int rem = wlen & 3;
        for (int tk = 0; tk < TG; ++tk) {
            const int t = r + 128 * q + 4 * tk;
            const float* rp = emb + (size_t)t * (size_t)V + wstart;  // 16B-aligned
            float s = 0.f, d0 = 0.f, d1 = 0.f;
            for (int j = tid; j < nb4; j += 256) {
                const int v4 = j << 2;
                const vfloat4 ev = __builtin_nontemporal_load((const vfloat4*)(rp + v4));
                float2 f[4];
                __builtin_memcpy(f, wf2 + (wstart + v4), 32);
                s += (ev.x + ev.y) + (ev.z + ev.w);
                d0 = fmaf(ev.x, f[0].x, d0);
                d0 = fmaf(ev.y, f[1].x, d0);
                d0 = fmaf(ev.z, f[2].x, d0);
                d0 = fmaf(ev.w, f[3].x, d0);
                d1 = fmaf(ev.x, f[0].y, d1);
                d1 = fmaf(ev.y, f[1].y, d1);
                d1 = fmaf(ev.z, f[2].y, d1);
                d1 = fmaf(ev.w, f[3].y, d1);
            }
            if (tid < rem) {
                const int v = (nb4 << 2) + tid;
                const float e = __builtin_nontemporal_load(rp + v);
                const float2 w = wf2[wstart + v];
                s += e; d0 = fmaf(e, w.x, d0); d1 = fmaf(e, w.y, d1);
            }
            #pragma unroll
            for (int off = 32; off > 0; off >>= 1) {
                s  += __shfl_xor(s,  off);
                d0 += __shfl_xor(d0, off);
                d1 += __shfl_xor(d1, off);
            }
            if ((tid & 63) == 0) {
                red[wv][tk][0] = s; red[wv][tk][1] = d0; red[wv][tk][2] = d1;
            }
        }
    }
    __syncthreads();

    if (tid < TG) {
        const float S  = (red[0][tid][0] + red[1][tid][0]) + (red[2][tid][0] + red[3][tid][0]);
        const float D0 = (red[0][tid][1] + red[1][tid][1]) + (red[2][tid][1] + red[3][tid][1]);
        const float D1 = (red[0][tid][2] + red[1][tid][2]) + (red[2][tid][2] + red[3][tid][2]);
        const int t = r + 128 * q + 4 * tid;
        part[(size_t)c * T + t] = make_float4(S, D0, D1, 0.f);
    }
}

// ---------------------------------------------------------------------------
// Kernel 3: finalize. out[t] = D/S + b. Fixed summation order.
// ---------------------------------------------------------------------------
__global__ __launch_bounds__(256) void finalize_kernel(
    const float4* __restrict__ part, const float* __restrict__ bcls,
    float2* __restrict__ out, const int T, const int NC)
{
    const int t = blockIdx.x * 256 + threadIdx.x;
    if (t >= T) return;
    float S = 0.f, D0 = 0.f, D1 = 0.f;
    for (int c = 0; c < NC; ++c) {
        float4 p = part[(size_t)c * T + t];
        S += p.x; D0 += p.y; D1 += p.z;
    }
    out[t] = make_float2(D0 / S + bcls[0], D1 / S + bcls[1]);
}

extern "C" void kernel_launch(void* const* d_in, const int* in_sizes, int n_in,
                              void* d_out, int out_size, void* d_ws, size_t ws_size,
                              hipStream_t stream) {
    const float* emb   = (const float*)d_in[0];   // [B,S,V] f32
    // d_in[1]: attention_masks (all-ones, unused by the math)
    const float* Wemb  = (const float*)d_in[2];   // [H,V] f32
    const float* tmask = (const float*)d_in[3];   // [V] f32
    const float* Wcls  = (const float*)d_in[4];   // [2,H] f32
    const float* bcls  = (const float*)d_in[5];   // [2] f32

    const int V  = in_sizes[3];                   // 50265 (V mod 4 == 1)
    const int T  = in_sizes[1];                   // B*S = 8192 (mult of 128)
    const int H  = in_sizes[2] / V;               // 768
    const int NC = (V + CHUNK - 1) / CHUNK;       // 13
    const int Vp = (V + 7) & ~7;

    // ws layout: [wf2: V float2][k2 partials: NC*T float4][k1 partials]
    float2* wf2 = (float2*)d_ws;
    const size_t wf2_b   = (((size_t)V * 8) + 255) & ~(size_t)255;
    const size_t k2p_b   = (((size_t)NC * T * 16) + 255) & ~(size_t)255;
    float4* k2part = (float4*)((char*)d_ws + wf2_b);
    const size_t off_k1p = wf2_b + k2p_b;
    float*  k1part = (float*)((char*)d_ws + off_k1p);

    const size_t per_g = (size_t)2 * Vp * 4;
    int NG = 0;
    if (ws_size > off_k1p) NG = (int)((ws_size - off_k1p) / per_g);
    if (NG > MAXNG) NG = MAXNG;

    if (NG >= 2) {
        const int NVT = (V + VT - 1) / VT;        // 25 -> 25*41 = 1025 blocks
        fuse_partial_kernel<<<NVT * NG, 256, 0, stream>>>(Wemb, Wcls, k1part, V, Vp, H, NG, NVT);
        fuse_reduce_kernel<<<(V + 255) / 256, 256, 0, stream>>>(k1part, tmask, wf2, V, Vp, NG);
    } else {
        fuse_weights_kernel<<<(V + 63) / 64, 256, 0, stream>>>(Wemb, tmask, Wcls, wf2, V, H);
    }

    // Kernel 2: class-grouped (chunk x 32-token) partial sums, nt emb loads
    const int blocks2 = NC * (T / TG);            // 13 * 256 = 3328
    partial_kernel<<<blocks2, 256, 0, stream>>>(emb, wf2, k2part, V, T, NC);

    // Kernel 3: finalize logits
    finalize_kernel<<<(T + 255) / 256, 256, 0, stream>>>(k2part, bcls, (float2*)d_out, T, NC);
}